// Round 5
// baseline (193.335 us; speedup 1.0000x reference)
//
#include <hip/hip_runtime.h>
#include <hip/hip_bf16.h>

#define BATCH 32
#define DIM   128
#define NPTS  2048
#define NCH   16          // 16-byte chunks (8 bf16) per point
#define BIGF  1e30f

// ws byte offsets; images are CHUNK-MAJOR: img[b][c][n] in 16B units
#define OFF_XT   0ull
#define OFF_YT   16777216ull
#define OFF_XN   33554432ull
#define OFF_YN   (OFF_XN + 262144ull)
#define OFF_RMIN (OFF_XN + 2ull * 262144ull)
#define OFF_CMIN (OFF_XN + 3ull * 262144ull)

typedef __bf16 bf16x8 __attribute__((ext_vector_type(8)));
typedef float  f32x16 __attribute__((ext_vector_type(16)));
typedef unsigned int u32;

#define ZERO16 {0.f,0.f,0.f,0.f,0.f,0.f,0.f,0.f,0.f,0.f,0.f,0.f,0.f,0.f,0.f,0.f}

__device__ __forceinline__ bool mask_is_i32(const void* m) {
  // mask[0][1] is guaranteed true (lens >= N/2 > 1); for int32 its byte 1 is 0.
  return ((const unsigned char*)m)[1] == 0;
}
__device__ __forceinline__ bool mask_at(const void* m, bool i32, int idx) {
  return i32 ? (((const int*)m)[idx] != 0) : (((const unsigned char*)m)[idx] != 0);
}

// async 16B global -> LDS (linear lane*16 destination)
__device__ __forceinline__ void gll16(const void* g, void* l) {
  __builtin_amdgcn_global_load_lds(
      (const __attribute__((address_space(1))) u32*)g,
      (__attribute__((address_space(3))) u32*)l, 16, 0, 0);
}

// -------- kernel 1: coalesced transpose -> chunk-major bf16 image + norms --------
// grid: 2 arr x 32 b x 16 nt = 1024 blocks, 256 threads; tile 128 d x 128 n
__global__ void chamfer_prep(const float* __restrict__ x, const float* __restrict__ y,
                             const void* __restrict__ mask, char* __restrict__ ws,
                             float* __restrict__ out) {
  __shared__ float buf[128 * 132];      // [d][n], pitch 132 words
  __shared__ float nrm_part[2][128];

  int blk = blockIdx.x;
  int arr = blk >> 9;
  int b   = (blk >> 4) & 31;
  int nt  = blk & 15;
  int n0  = nt << 7;
  int tid = threadIdx.x;
  bool i32m = mask_is_i32(mask);

  if (blk == 0 && tid == 0) out[0] = 0.f;

  float*    nrm  = (float*)(ws + (arr ? OFF_YN : OFF_XN));
  unsigned* cmin = (unsigned*)(ws + OFF_CMIN);

  // prefix mask: tile fully invalid iff its first point is invalid.
  // Then only BIG norms matter (image content is don't-care given BIG norms).
  if (!mask_at(mask, i32m, b * NPTS + n0)) {
    if (tid < 128) {
      nrm[b * NPTS + n0 + tid] = BIGF;
      if (arr) cmin[b * NPTS + n0 + tid] = __float_as_uint(BIGF);
    }
    return;
  }

  const float* src = (arr ? y : x) + (size_t)b * DIM * NPTS;
#pragma unroll
  for (int k = 0; k < 16; ++k) {
    int idx = k * 256 + tid;            // 128 d x 32 float4-cols
    int d = idx >> 5, c4 = idx & 31;
    *(float4*)&buf[d * 132 + c4 * 4] =
        *(const float4*)(src + (size_t)d * NPTS + n0 + c4 * 4);
  }
  __syncthreads();

  int n = tid & 127, half = tid >> 7;
  char* imgbase = ws + (arr ? OFF_YT : OFF_XT);
  float sq = 0.f;
#pragma unroll
  for (int cl = 0; cl < 8; ++cl) {
    unsigned short h[8];
#pragma unroll
    for (int q = 0; q < 8; ++q) {
      float v = buf[(half * 64 + cl * 8 + q) * 132 + n];
      __hip_bfloat16 bv = __float2bfloat16(v);
      h[q] = *(unsigned short*)&bv;
      float vb = __bfloat162float(bv);
      sq = fmaf(vb, vb, sq);            // norm from ROUNDED value (matches MFMA)
    }
    uint4 pk;
    pk.x = h[0] | ((unsigned)h[1] << 16);
    pk.y = h[2] | ((unsigned)h[3] << 16);
    pk.z = h[4] | ((unsigned)h[5] << 16);
    pk.w = h[6] | ((unsigned)h[7] << 16);
    int cg = half * 8 + cl;
    // chunk-major: consecutive n lanes -> contiguous 1KB writes
    *(uint4*)(imgbase + (((size_t)(b * NCH + cg) * NPTS + n0 + n) << 4)) = pk;
  }
  nrm_part[half][n] = sq;
  __syncthreads();
  if (half == 0) {
    float tot = nrm_part[0][n] + nrm_part[1][n];
    int row = n0 + n;
    bool valid = mask_at(mask, i32m, b * NPTS + row);
    nrm[b * NPTS + row] = valid ? tot : BIGF;
    if (arr) cmin[b * NPTS + row] = __float_as_uint(BIGF);
  }
}

// -------- kernel 2: MFMA distance + mins (len-bounded, gll-staged) --------
__global__ __launch_bounds__(512, 1)
void chamfer_dist(char* __restrict__ ws, const void* __restrict__ mask) {
  __shared__ __align__(16) char ysl[2][NCH * 256 * 16];  // 2 x 64 KB, chunk-major
  __shared__ unsigned colmin_lds[NPTS];                  // 8 KB
  __shared__ int lred[8];

  int blk = blockIdx.x;
  int b  = blk & 31;            // batch-fast: same-b i-blocks share an XCD L2
  int it = blk >> 5;
  int i0 = it << 8;
  int tid = threadIdx.x, lane = tid & 63, w = tid >> 6;
  int qrow = w >> 1, qcol = w & 1, la31 = lane & 31, la5 = lane >> 5;

  // len = popcount(mask[b])
  bool i32m = mask_is_i32(mask);
  int cnt = 0;
#pragma unroll
  for (int k = 0; k < 4; ++k)
    cnt += mask_at(mask, i32m, b * NPTS + k * 512 + tid) ? 1 : 0;
#pragma unroll
  for (int s = 1; s < 64; s <<= 1) cnt += __shfl_xor(cnt, s);
  if (lane == 0) lred[w] = cnt;
  __syncthreads();
  int len = 0;
#pragma unroll
  for (int k = 0; k < 8; ++k) len += lred[k];
  if (i0 >= len) return;        // uniform early-exit: block contributes nothing

  const char* xTb = ws + OFF_XT + ((size_t)b * NCH * NPTS << 4);
  const char* yTb = ws + OFF_YT + ((size_t)b * NCH * NPTS << 4);
  const float* xng = (const float*)(ws + OFF_XN) + b * NPTS;
  const float* yng = (const float*)(ws + OFF_YN) + b * NPTS;
  float*    rowming = (float*)(ws + OFF_RMIN) + b * NPTS;
  unsigned* colming = (unsigned*)(ws + OFF_CMIN) + b * NPTS;

#pragma unroll
  for (int k = 0; k < 4; ++k)
    colmin_lds[k * 512 + tid] = __float_as_uint(BIGF);

  // A fragments -> registers once (coalesced chunk-major reads, reused all jt)
  int r0 = i0 + qrow * 64 + la31;
  bf16x8 Areg0[8], Areg1[8];
#pragma unroll
  for (int kc = 0; kc < 8; ++kc) {
    int c = kc * 2 + la5;
    Areg0[kc] = *(const bf16x8*)(xTb + (((size_t)c * NPTS + r0) << 4));
    Areg1[kc] = *(const bf16x8*)(xTb + (((size_t)c * NPTS + r0 + 32) << 4));
  }

  // xn for this wave's rows (C/D layout: row=(r&3)+8*(r>>2)+4*la5)
  float xnr[2][16], rmin[2][16];
#pragma unroll
  for (int fm = 0; fm < 2; ++fm)
#pragma unroll
    for (int r = 0; r < 16; ++r) {
      int row = qrow * 64 + fm * 32 + (r & 3) + ((r >> 2) << 3) + (la5 << 2);
      xnr[fm][r] = xng[i0 + row];
      rmin[fm][r] = BIGF;       // tracks min_j(yn_j - 2*dot); xn added at end
    }

  int nT = (len + 255) >> 8;    // 256-col tiles

  // stage tile 0 via async global->LDS
#pragma unroll
  for (int k = 0; k < 8; ++k) {
    int idx = k * 512 + tid;    // c = idx>>8, jl = idx&255
    gll16(yTb + (((size_t)(idx >> 8) * NPTS + (idx & 255)) << 4),
          &ysl[0][idx * 16]);
  }
  __syncthreads();

  for (int t = 0; t < nT; ++t) {
    int cur = t & 1;
    if (t + 1 < nT) {           // T14: issue next tile before compute
      int j0n = (t + 1) << 8;
#pragma unroll
      for (int k = 0; k < 8; ++k) {
        int idx = k * 512 + tid;
        gll16(yTb + (((size_t)(idx >> 8) * NPTS + j0n + (idx & 255)) << 4),
              &ysl[cur ^ 1][idx * 16]);
      }
    }
    const char* ybuf = (const char*)ysl[cur];
#pragma unroll
    for (int sub = 0; sub < 2; ++sub) {
      int jbase = (sub << 7) + qcol * 64;
      int j0t = (t << 8) + jbase;
      float ynr0 = yng[j0t + la31];
      float ynr1 = yng[j0t + 32 + la31];

      f32x16 acc00 = ZERO16, acc01 = ZERO16, acc10 = ZERO16, acc11 = ZERO16;
#pragma unroll
      for (int kc = 0; kc < 8; ++kc) {
        int c = kc * 2 + la5;
        int boff = (c * 256 + jbase + la31) << 4;
        bf16x8 b0 = *(const bf16x8*)(ybuf + boff);
        bf16x8 b1 = *(const bf16x8*)(ybuf + boff + (32 << 4));
        acc00 = __builtin_amdgcn_mfma_f32_32x32x16_bf16(Areg0[kc], b0, acc00, 0, 0, 0);
        acc01 = __builtin_amdgcn_mfma_f32_32x32x16_bf16(Areg0[kc], b1, acc01, 0, 0, 0);
        acc10 = __builtin_amdgcn_mfma_f32_32x32x16_bf16(Areg1[kc], b0, acc10, 0, 0, 0);
        acc11 = __builtin_amdgcn_mfma_f32_32x32x16_bf16(Areg1[kc], b1, acc11, 0, 0, 0);
      }
      // epilogue: u = yn - 2*dot; rmin += nothing (xn folded at end); cm = xn + u
      float cm0 = BIGF, cm1 = BIGF;
#pragma unroll
      for (int r = 0; r < 16; ++r) {
        float u00 = fmaf(-2.f, acc00[r], ynr0);
        float u01 = fmaf(-2.f, acc01[r], ynr1);
        float u10 = fmaf(-2.f, acc10[r], ynr0);
        float u11 = fmaf(-2.f, acc11[r], ynr1);
        rmin[0][r] = fminf(rmin[0][r], fminf(u00, u01));
        rmin[1][r] = fminf(rmin[1][r], fminf(u10, u11));
        cm0 = fminf(cm0, fminf(u00 + xnr[0][r], u10 + xnr[1][r]));
        cm1 = fminf(cm1, fminf(u01 + xnr[0][r], u11 + xnr[1][r]));
      }
      cm0 = fminf(cm0, __shfl_xor(cm0, 32));
      cm1 = fminf(cm1, __shfl_xor(cm1, 32));
      if (lane < 32) {
        atomicMin(&colmin_lds[j0t + la31],      __float_as_uint(fmaxf(cm0, 0.f)));
        atomicMin(&colmin_lds[j0t + 32 + la31], __float_as_uint(fmaxf(cm1, 0.f)));
      }
    }
    __syncthreads();            // also drains next-tile gll (vmcnt 0)
  }

  // merge colmin (only the j range we touched)
  int jmax = nT << 8; if (jmax > NPTS) jmax = NPTS;
  for (int idx = tid; idx < jmax; idx += 512)
    atomicMin(&colming[idx], colmin_lds[idx]);

  // rowmin: reduce across 32 j-lanes, add xn, clamp, write (rows owned by block)
#pragma unroll
  for (int fm = 0; fm < 2; ++fm)
#pragma unroll
    for (int r = 0; r < 16; ++r) {
      float v = rmin[fm][r];
      v = fminf(v, __shfl_xor(v, 1));
      v = fminf(v, __shfl_xor(v, 2));
      v = fminf(v, __shfl_xor(v, 4));
      v = fminf(v, __shfl_xor(v, 8));
      v = fminf(v, __shfl_xor(v, 16));
      if (la31 == 0) {
        int row = qrow * 64 + fm * 32 + (r & 3) + ((r >> 2) << 3) + (la5 << 2);
        rowming[i0 + row] = fmaxf(v + xnr[fm][r], 0.f);
      }
    }
}

// ---------------- kernel 3: masked sums + mean ----------------
__global__ void chamfer_reduce(const char* __restrict__ ws, const void* __restrict__ mask,
                               float* __restrict__ out) {
  __shared__ float red[256];
  int blk = blockIdx.x;
  int b = blk >> 2, sl = blk & 3;
  int tid = threadIdx.x;
  bool i32m = mask_is_i32(mask);
  const float*    rowmin = (const float*)(ws + OFF_RMIN) + b * NPTS;
  const unsigned* colmin = (const unsigned*)(ws + OFF_CMIN) + b * NPTS;
  float s = 0.f;
#pragma unroll
  for (int k = 0; k < 2; ++k) {
    int i = sl * 512 + k * 256 + tid;
    if (mask_at(mask, i32m, b * NPTS + i))
      s += rowmin[i] + __uint_as_float(colmin[i]);
  }
  red[tid] = s;
  __syncthreads();
  for (int st = 128; st > 0; st >>= 1) {
    if (tid < st) red[tid] += red[tid + st];
    __syncthreads();
  }
  if (tid == 0) atomicAdd(out, red[0] * (1.f / BATCH));
}

extern "C" void kernel_launch(void* const* d_in, const int* in_sizes, int n_in,
                              void* d_out, int out_size, void* d_ws, size_t ws_size,
                              hipStream_t stream) {
  const float* x = (const float*)d_in[0];
  const float* y = (const float*)d_in[1];
  const void* mask = d_in[2];
  float* out = (float*)d_out;
  char* ws = (char*)d_ws;

  chamfer_prep<<<1024, 256, 0, stream>>>(x, y, mask, ws, out);
  chamfer_dist<<<256, 512, 0, stream>>>(ws, mask);
  chamfer_reduce<<<128, 256, 0, stream>>>(ws, mask, out);
}

// Round 6
// 146.397 us; speedup vs baseline: 1.3206x; 1.3206x over previous
//
#include <hip/hip_runtime.h>
#include <hip/hip_bf16.h>

#define BATCH 32
#define DIM   128
#define NPTS  2048
#define NCH   16          // 16-byte chunks (8 bf16) per point
#define BIGF  1e30f

// ws byte offsets; images are CHUNK-MAJOR: img[b][c][n] in 16B units
#define OFF_XT   0ull
#define OFF_YT   16777216ull
#define OFF_XN   33554432ull
#define OFF_YN   (OFF_XN + 262144ull)
#define OFF_RMIN (OFF_XN + 2ull * 262144ull)
#define OFF_CMIN (OFF_XN + 3ull * 262144ull)

typedef __bf16 bf16x8 __attribute__((ext_vector_type(8)));
typedef float  f32x16 __attribute__((ext_vector_type(16)));

#define ZERO16 {0.f,0.f,0.f,0.f,0.f,0.f,0.f,0.f,0.f,0.f,0.f,0.f,0.f,0.f,0.f,0.f}

__device__ __forceinline__ bool mask_is_i32(const void* m) {
  // mask[0][1] is guaranteed true (lens >= N/2 > 1); for int32 its byte 1 is 0.
  return ((const unsigned char*)m)[1] == 0;
}
__device__ __forceinline__ bool mask_at(const void* m, bool i32, int idx) {
  return i32 ? (((const int*)m)[idx] != 0) : (((const unsigned char*)m)[idx] != 0);
}

// -------- kernel 1: coalesced transpose -> chunk-major bf16 image + norms --------
// grid: 2 arr x 32 b x 16 nt = 1024 blocks, 256 threads; tile 128 d x 128 n
__global__ void chamfer_prep(const float* __restrict__ x, const float* __restrict__ y,
                             const void* __restrict__ mask, char* __restrict__ ws,
                             float* __restrict__ out) {
  __shared__ float buf[128 * 132];      // [d][n], pitch 132 words
  __shared__ float nrm_part[2][128];

  int blk = blockIdx.x;
  int arr = blk >> 9;
  int b   = (blk >> 4) & 31;
  int nt  = blk & 15;
  int n0  = nt << 7;
  int tid = threadIdx.x;
  bool i32m = mask_is_i32(mask);

  if (blk == 0 && tid == 0) out[0] = 0.f;

  float*    nrm  = (float*)(ws + (arr ? OFF_YN : OFF_XN));
  unsigned* cmin = (unsigned*)(ws + OFF_CMIN);

  // prefix mask: tile fully invalid iff its first point is invalid.
  // Then only BIG norms matter (image content is don't-care given BIG norms).
  if (!mask_at(mask, i32m, b * NPTS + n0)) {
    if (tid < 128) {
      nrm[b * NPTS + n0 + tid] = BIGF;
      if (arr) cmin[b * NPTS + n0 + tid] = __float_as_uint(BIGF);
    }
    return;
  }

  const float* src = (arr ? y : x) + (size_t)b * DIM * NPTS;
#pragma unroll
  for (int k = 0; k < 16; ++k) {
    int idx = k * 256 + tid;            // 128 d x 32 float4-cols
    int d = idx >> 5, c4 = idx & 31;
    *(float4*)&buf[d * 132 + c4 * 4] =
        *(const float4*)(src + (size_t)d * NPTS + n0 + c4 * 4);
  }
  __syncthreads();

  int n = tid & 127, half = tid >> 7;
  char* imgbase = ws + (arr ? OFF_YT : OFF_XT);
  float sq = 0.f;
#pragma unroll
  for (int cl = 0; cl < 8; ++cl) {
    unsigned short h[8];
#pragma unroll
    for (int q = 0; q < 8; ++q) {
      float v = buf[(half * 64 + cl * 8 + q) * 132 + n];
      __hip_bfloat16 bv = __float2bfloat16(v);
      h[q] = *(unsigned short*)&bv;
      float vb = __bfloat162float(bv);
      sq = fmaf(vb, vb, sq);            // norm from ROUNDED value (matches MFMA)
    }
    uint4 pk;
    pk.x = h[0] | ((unsigned)h[1] << 16);
    pk.y = h[2] | ((unsigned)h[3] << 16);
    pk.z = h[4] | ((unsigned)h[5] << 16);
    pk.w = h[6] | ((unsigned)h[7] << 16);
    int cg = half * 8 + cl;
    // chunk-major: consecutive n lanes -> contiguous 1KB writes
    *(uint4*)(imgbase + (((size_t)(b * NCH + cg) * NPTS + n0 + n) << 4)) = pk;
  }
  nrm_part[half][n] = sq;
  __syncthreads();
  if (half == 0) {
    float tot = nrm_part[0][n] + nrm_part[1][n];
    int row = n0 + n;
    bool valid = mask_at(mask, i32m, b * NPTS + row);
    nrm[b * NPTS + row] = valid ? tot : BIGF;
    if (arr) cmin[b * NPTS + row] = __float_as_uint(BIGF);
  }
}

// -------- kernel 2: MFMA distance + mins (r3 skeleton + chunk-major + len-bound) --------
__global__ __launch_bounds__(512, 2)
void chamfer_dist(char* __restrict__ ws, const void* __restrict__ mask) {
  __shared__ __align__(16) char ysl[2][NCH * 128 * 16];  // 2 x 32 KB, chunk-major
  __shared__ unsigned colmin_lds[NPTS];                  // 8 KB
  __shared__ int lred[8];

  int blk = blockIdx.x;
  int b  = blk & 31;            // batch-fast: same-b i-blocks share an XCD L2
  int it = blk >> 5;
  int i0 = it << 8;
  int tid = threadIdx.x, lane = tid & 63, w = tid >> 6;
  int qrow = w >> 1, qcol = w & 1, la31 = lane & 31, la5 = lane >> 5;

  // len = popcount(mask[b])
  bool i32m = mask_is_i32(mask);
  int cnt = 0;
#pragma unroll
  for (int k = 0; k < 4; ++k)
    cnt += mask_at(mask, i32m, b * NPTS + k * 512 + tid) ? 1 : 0;
#pragma unroll
  for (int s = 1; s < 64; s <<= 1) cnt += __shfl_xor(cnt, s);
  if (lane == 0) lred[w] = cnt;
  __syncthreads();
  int len = 0;
#pragma unroll
  for (int k = 0; k < 8; ++k) len += lred[k];
  if (i0 >= len) return;        // uniform early-exit: block contributes nothing

  const char* xTb = ws + OFF_XT + ((size_t)b * NCH * NPTS << 4);
  const char* yTb = ws + OFF_YT + ((size_t)b * NCH * NPTS << 4);
  const float* xng = (const float*)(ws + OFF_XN) + b * NPTS;
  const float* yng = (const float*)(ws + OFF_YN) + b * NPTS;
  float*    rowming = (float*)(ws + OFF_RMIN) + b * NPTS;
  unsigned* colming = (unsigned*)(ws + OFF_CMIN) + b * NPTS;

#pragma unroll
  for (int k = 0; k < 4; ++k)
    colmin_lds[k * 512 + tid] = __float_as_uint(BIGF);

  // A fragments -> registers once (coalesced chunk-major reads, reused all jt)
  int r0 = i0 + qrow * 64 + la31;
  bf16x8 Areg0[8], Areg1[8];
#pragma unroll
  for (int kc = 0; kc < 8; ++kc) {
    int c = kc * 2 + la5;
    Areg0[kc] = *(const bf16x8*)(xTb + (((size_t)c * NPTS + r0) << 4));
    Areg1[kc] = *(const bf16x8*)(xTb + (((size_t)c * NPTS + r0 + 32) << 4));
  }

  // xn for this wave's rows (C/D layout: row=(r&3)+8*(r>>2)+4*la5)
  float xnr[2][16], rmin[2][16];
#pragma unroll
  for (int fm = 0; fm < 2; ++fm)
#pragma unroll
    for (int r = 0; r < 16; ++r) {
      int row = qrow * 64 + fm * 32 + (r & 3) + ((r >> 2) << 3) + (la5 << 2);
      xnr[fm][r] = xng[i0 + row];
      rmin[fm][r] = BIGF;       // tracks min_j(yn_j - 2*dot); xn added at end
    }

  int nT = (len + 127) >> 7;    // 128-col tiles

  // stage tile 0: linear copy of chunk-major image (conflict-free)
#pragma unroll
  for (int k = 0; k < 4; ++k) {
    int idx = k * 512 + tid;    // c = idx>>7, jl = idx&127
    *(uint4*)(ysl[0] + idx * 16) =
        *(const uint4*)(yTb + (((size_t)(idx >> 7) * NPTS + (idx & 127)) << 4));
  }
  __syncthreads();

  for (int jt = 0; jt < nT; ++jt) {
    int cur = jt & 1;
    // T14 async split: issue next tile's global loads before compute
    uint4 stg0, stg1, stg2, stg3;
    if (jt + 1 < nT) {
      int j0n = (jt + 1) << 7;
      int i0d = tid, i1d = 512 + tid, i2d = 1024 + tid, i3d = 1536 + tid;
      stg0 = *(const uint4*)(yTb + (((size_t)(i0d >> 7) * NPTS + j0n + (i0d & 127)) << 4));
      stg1 = *(const uint4*)(yTb + (((size_t)(i1d >> 7) * NPTS + j0n + (i1d & 127)) << 4));
      stg2 = *(const uint4*)(yTb + (((size_t)(i2d >> 7) * NPTS + j0n + (i2d & 127)) << 4));
      stg3 = *(const uint4*)(yTb + (((size_t)(i3d >> 7) * NPTS + j0n + (i3d & 127)) << 4));
    }
    int j0t = (jt << 7) + qcol * 64;
    float ynr0 = yng[j0t + la31];
    float ynr1 = yng[j0t + 32 + la31];

    const char* ybuf = (const char*)ysl[cur];
    f32x16 acc00 = ZERO16, acc01 = ZERO16, acc10 = ZERO16, acc11 = ZERO16;
#pragma unroll
    for (int kc = 0; kc < 8; ++kc) {
      int boff = ((kc * 2 + la5) * 128 + qcol * 64 + la31) << 4;
      bf16x8 b0 = *(const bf16x8*)(ybuf + boff);
      bf16x8 b1 = *(const bf16x8*)(ybuf + boff + (32 << 4));
      acc00 = __builtin_amdgcn_mfma_f32_32x32x16_bf16(Areg0[kc], b0, acc00, 0, 0, 0);
      acc01 = __builtin_amdgcn_mfma_f32_32x32x16_bf16(Areg0[kc], b1, acc01, 0, 0, 0);
      acc10 = __builtin_amdgcn_mfma_f32_32x32x16_bf16(Areg1[kc], b0, acc10, 0, 0, 0);
      acc11 = __builtin_amdgcn_mfma_f32_32x32x16_bf16(Areg1[kc], b1, acc11, 0, 0, 0);
    }
    // epilogue: u = yn - 2*dot; xn folded at the end; clamp deferred
    float cm0 = BIGF, cm1 = BIGF;
#pragma unroll
    for (int r = 0; r < 16; ++r) {
      float u00 = fmaf(-2.f, acc00[r], ynr0);
      float u01 = fmaf(-2.f, acc01[r], ynr1);
      float u10 = fmaf(-2.f, acc10[r], ynr0);
      float u11 = fmaf(-2.f, acc11[r], ynr1);
      rmin[0][r] = fminf(rmin[0][r], fminf(u00, u01));
      rmin[1][r] = fminf(rmin[1][r], fminf(u10, u11));
      cm0 = fminf(cm0, fminf(u00 + xnr[0][r], u10 + xnr[1][r]));
      cm1 = fminf(cm1, fminf(u01 + xnr[0][r], u11 + xnr[1][r]));
    }
    cm0 = fminf(cm0, __shfl_xor(cm0, 32));
    cm1 = fminf(cm1, __shfl_xor(cm1, 32));
    if (lane < 32) {
      atomicMin(&colmin_lds[j0t + la31],      __float_as_uint(fmaxf(cm0, 0.f)));
      atomicMin(&colmin_lds[j0t + 32 + la31], __float_as_uint(fmaxf(cm1, 0.f)));
    }
    // land the prefetched tile into the other buffer (linear, conflict-free)
    if (jt + 1 < nT) {
      char* dst = (char*)ysl[cur ^ 1];
      *(uint4*)(dst + (size_t)(tid)        * 16) = stg0;
      *(uint4*)(dst + (size_t)(512  + tid) * 16) = stg1;
      *(uint4*)(dst + (size_t)(1024 + tid) * 16) = stg2;
      *(uint4*)(dst + (size_t)(1536 + tid) * 16) = stg3;
    }
    __syncthreads();
  }

  // merge colmin (only the j range we touched)
  int jmax = nT << 7; if (jmax > NPTS) jmax = NPTS;
  for (int idx = tid; idx < jmax; idx += 512)
    atomicMin(&colming[idx], colmin_lds[idx]);

  // rowmin: reduce across 32 j-lanes, add xn, clamp, write (rows owned by block)
#pragma unroll
  for (int fm = 0; fm < 2; ++fm)
#pragma unroll
    for (int r = 0; r < 16; ++r) {
      float v = rmin[fm][r];
      v = fminf(v, __shfl_xor(v, 1));
      v = fminf(v, __shfl_xor(v, 2));
      v = fminf(v, __shfl_xor(v, 4));
      v = fminf(v, __shfl_xor(v, 8));
      v = fminf(v, __shfl_xor(v, 16));
      if (la31 == 0) {
        int row = qrow * 64 + fm * 32 + (r & 3) + ((r >> 2) << 3) + (la5 << 2);
        rowming[i0 + row] = fmaxf(v + xnr[fm][r], 0.f);
      }
    }
}

// ---------------- kernel 3: masked sums + mean ----------------
__global__ void chamfer_reduce(const char* __restrict__ ws, const void* __restrict__ mask,
                               float* __restrict__ out) {
  __shared__ float red[256];
  int blk = blockIdx.x;
  int b = blk >> 2, sl = blk & 3;
  int tid = threadIdx.x;
  bool i32m = mask_is_i32(mask);
  const float*    rowmin = (const float*)(ws + OFF_RMIN) + b * NPTS;
  const unsigned* colmin = (const unsigned*)(ws + OFF_CMIN) + b * NPTS;
  float s = 0.f;
#pragma unroll
  for (int k = 0; k < 2; ++k) {
    int i = sl * 512 + k * 256 + tid;
    if (mask_at(mask, i32m, b * NPTS + i))
      s += rowmin[i] + __uint_as_float(colmin[i]);
  }
  red[tid] = s;
  __syncthreads();
  for (int st = 128; st > 0; st >>= 1) {
    if (tid < st) red[tid] += red[tid + st];
    __syncthreads();
  }
  if (tid == 0) atomicAdd(out, red[0] * (1.f / BATCH));
}

extern "C" void kernel_launch(void* const* d_in, const int* in_sizes, int n_in,
                              void* d_out, int out_size, void* d_ws, size_t ws_size,
                              hipStream_t stream) {
  const float* x = (const float*)d_in[0];
  const float* y = (const float*)d_in[1];
  const void* mask = d_in[2];
  float* out = (float*)d_out;
  char* ws = (char*)d_ws;

  chamfer_prep<<<1024, 256, 0, stream>>>(x, y, mask, ws, out);
  chamfer_dist<<<256, 512, 0, stream>>>(ws, mask);
  chamfer_reduce<<<128, 256, 0, stream>>>(ws, mask, out);
}